// Round 6
// baseline (1892.476 us; speedup 1.0000x reference)
//
#include <hip/hip_runtime.h>
#include <hip/hip_bf16.h>
#include <cstdint>

#define T_TOK 32768
#define DIMD  1024
#define HID   2048
#define HSH   1024
#define NE    4

typedef __attribute__((ext_vector_type(8))) short short8;
typedef __attribute__((ext_vector_type(4))) float f32x4;

typedef const __attribute__((address_space(1))) void* gas_ptr;
typedef __attribute__((address_space(3))) void* las_ptr;

__device__ __forceinline__ void load_lds16(const void* g, void* l) {
  __builtin_amdgcn_global_load_lds((gas_ptr)g, (las_ptr)l, 16, 0, 0);
}

__device__ __forceinline__ unsigned short bf16r(float f) {
  union { float f; uint32_t u; } c; c.f = f;
  uint32_t u = c.u;
  uint32_t r = (u + 0x7FFFu + ((u >> 16) & 1u)) >> 16;
  return (unsigned short)r;
}

__device__ __forceinline__ float bf2f(unsigned short u) {
  union { uint32_t u; float f; } c; c.u = ((uint32_t)u) << 16; return c.f;
}

// ---------------- transpose fp32 [R][C] -> bf16 [C][R] ----------------
template <int TMODE>
__global__ __launch_bounds__(256) void transpose_bf16_kernel(
    const float* __restrict__ src, unsigned short* __restrict__ dst,
    int R, int C, long srcBS, long dstBS) {
  __shared__ float tile[32][33];
  const float* s = src + (long)blockIdx.z * srcBS;
  unsigned short* d = dst + (long)blockIdx.z * dstBS;
  int c0 = blockIdx.x * 32, r0 = blockIdx.y * 32;
  int tx = threadIdx.x, ty = threadIdx.y;
#pragma unroll
  for (int i = 0; i < 4; i++)
    tile[ty + i * 8][tx] = s[(long)(r0 + ty + i * 8) * C + c0 + tx];
  __syncthreads();
#pragma unroll
  for (int i = 0; i < 4; i++) {
    int c = c0 + ty + i * 8;
    int orow = (TMODE == 0) ? c : (((c >> 6) << 7) + (c & 63) + (TMODE == 2 ? 64 : 0));
    d[(long)orow * R + r0 + tx] = bf16r(tile[tx][ty + i * 8]);
  }
}

// ---------------- gating + x cast, block-aggregated list build ----------------
__global__ __launch_bounds__(256) void gating_cast_kernel(
    const float* __restrict__ x, const float* __restrict__ gw,
    unsigned short* __restrict__ xb,
    int* __restrict__ list, float* __restrict__ cw, int* __restrict__ cnt) {
  __shared__ int   se[128];
  __shared__ float sw[128];
  __shared__ int   sloc[128];
  __shared__ int   sbase[NE];
  const int lane = threadIdx.x & 63;
  const int wid = threadIdx.x >> 6;
  const int tb = blockIdx.x * 64;

  for (int j = 0; j < 16; j++) {
    const int tl = wid * 16 + j;
    const long t = tb + tl;
    const float4* xp = (const float4*)(x + t * DIMD);
    double acc[NE] = {0.0, 0.0, 0.0, 0.0};
    float4 xv[4];
#pragma unroll
    for (int i = 0; i < 4; i++) {
      xv[i] = xp[i * 64 + lane];
#pragma unroll
      for (int e = 0; e < NE; e++) {
        float4 gv = ((const float4*)(gw + e * DIMD))[i * 64 + lane];
        acc[e] += (double)xv[i].x * gv.x + (double)xv[i].y * gv.y +
                  (double)xv[i].z * gv.z + (double)xv[i].w * gv.w;
      }
    }
    ushort4* xbp = (ushort4*)(xb + t * DIMD);
#pragma unroll
    for (int i = 0; i < 4; i++) {
      ushort4 o;
      o.x = bf16r(xv[i].x); o.y = bf16r(xv[i].y);
      o.z = bf16r(xv[i].z); o.w = bf16r(xv[i].w);
      xbp[i * 64 + lane] = o;
    }
#pragma unroll
    for (int e = 0; e < NE; e++)
#pragma unroll
      for (int s = 32; s > 0; s >>= 1) acc[e] += __shfl_xor(acc[e], s, 64);
    if (lane == 0) {
      double m = acc[0];
      for (int e = 1; e < NE; e++) if (acc[e] > m) m = acc[e];
      double p[NE]; double s = 0.0;
      for (int e = 0; e < NE; e++) { p[e] = exp(acc[e] - m); s += p[e]; }
      int e0 = 0;
      for (int e = 1; e < NE; e++) if (p[e] > p[e0]) e0 = e;
      int e1 = (e0 == 0) ? 1 : 0;
      for (int e = 0; e < NE; e++) { if (e == e0) continue; if (p[e] > p[e1]) e1 = e; }
      se[tl * 2]     = e0; sw[tl * 2]     = (float)(p[e0] / s);
      se[tl * 2 + 1] = e1; sw[tl * 2 + 1] = (float)(p[e1] / s);
    }
  }
  __syncthreads();
  const int tid = threadIdx.x;
  if (tid < NE) {
    int c = 0;
    for (int s = 0; s < 128; s++)
      if (se[s] == tid) sloc[s] = c++;
    sbase[tid] = atomicAdd(&cnt[tid], c);
  }
  __syncthreads();
  if (tid < 128) {
    int e = se[tid];
    int pos = sbase[e] + sloc[tid];
    list[e * T_TOK + pos] = ((tb + (tid >> 1)) << 1) | (tid & 1);
    cw[tb * 2 + tid] = sw[tid];
  }
}

// ---------------- 256x256x64 8-wave GEMM, 8-phase schedule ----------------
// Block mapping: bijective XCD chunking, then each chunk's consecutive 32
// wgids form a 4n x 8m supertile -> per XCD resident set shares 4 B-panels
// and 8 A-panels through that XCD's L2 (beyond-L2 staging 528->192 MB).
// Requires gx%4==0, gy%8==0, nwg%32==0 (all launch shapes satisfy).
template <int EPI, int AMODE>
__global__ __launch_bounds__(512, 2) void gemm256_kernel(
    const unsigned short* __restrict__ A, const unsigned short* __restrict__ Bt,
    void* __restrict__ outp, const int* __restrict__ list,
    const int* __restrict__ cntp, int K, int OutW) {
  extern __shared__ char ldsb[];  // 131072 bytes
  const int tid = threadIdx.x, lane = tid & 63;
  const int wid = tid >> 6;
  const int wm = wid >> 2, wn = wid & 3;
  const int l15 = lane & 15, l4 = lane >> 4;

  // T1: bijective XCD chunk swizzle
  const int gx = gridDim.x, gy = gridDim.y;
  const int nwg = gx * gy;
  const int orig = blockIdx.y * gx + blockIdx.x;
  const int q8 = nwg >> 3, r8 = nwg & 7, xcd = orig & 7, loc = orig >> 3;
  const int wgid = (xcd < r8 ? xcd * (q8 + 1) : r8 * (q8 + 1) + (xcd - r8) * q8) + loc;
  // supertile 4n x 8m decomposition
  const int s = wgid >> 5, r = wgid & 31;
  const int scols = gx >> 2;
  const int sx = s % scols, sy = s / scols;
  const int n0 = (sx * 4 + (r & 3)) * 256;
  const int m0 = (sy * 8 + (r >> 2)) * 256;

  int M = 0x7fffffff;
  if (AMODE != 0) {
    M = *cntp;
    if (m0 >= M) return;
  }

  const unsigned short* pA[4];
  const unsigned short* pB[4];
  {
    const int rb = tid >> 3;
    const int cs = (tid & 7) ^ (rb & 7);
#pragma unroll
    for (int j = 0; j < 4; j++) {
      int rr = j * 64 + rb;
      int arow = m0 + rr;
      long ga;
      if (AMODE == 1)      ga = list[arow < M ? arow : M - 1] >> 1;
      else if (AMODE == 2) ga = (arow < M ? arow : M - 1);
      else                 ga = arow;
      pA[j] = A + ga * (long)K + cs * 8;
      pB[j] = Bt + (long)(n0 + rr) * K + cs * 8;
    }
  }

  auto stageA = [&](int buf, int half, int koff) {
    char* d = ldsb + buf * 65536 + half * 16384 + tid * 16;
    load_lds16(pA[half * 2 + 0] + koff, d);
    load_lds16(pA[half * 2 + 1] + koff, d + 8192);
  };
  auto stageB = [&](int buf, int half, int koff) {
    char* d = ldsb + buf * 65536 + 32768 + half * 16384 + tid * 16;
    load_lds16(pB[half * 2 + 0] + koff, d);
    load_lds16(pB[half * 2 + 1] + koff, d + 8192);
  };

  const int sw8 = l15 & 7;
  const int abase = (wm * 16 + l15) * 128 + ((l4 ^ sw8) * 16);
  const int bbase = 32768 + (wn * 16 + l15) * 128 + ((l4 ^ sw8) * 16);

  f32x4 acc[8][4] = {};
  const int nt = K >> 6;

  stageA(0, 0, 0); stageA(0, 1, 0); stageB(0, 0, 0); stageB(0, 1, 0);
  if (nt > 1) { stageA(1, 0, 64); stageB(1, 0, 64); stageA(1, 1, 64); }
  if (nt > 1) asm volatile("s_waitcnt vmcnt(6)" ::: "memory");
  else        asm volatile("s_waitcnt vmcnt(0)" ::: "memory");
  __builtin_amdgcn_sched_barrier(0);
  __builtin_amdgcn_s_barrier();

  for (int kt = 0; kt < nt; ++kt) {
    const int buf = kt & 1;
    const char* Lb = ldsb + buf * 65536;
    const int ko2 = (kt + 2) * 64;
    short8 afL[2][4], afH[2][4], bfL[2][2], bfH[2][2];

    // ---------- P1: Q1 (fmL x fnL) ----------
#pragma unroll
    for (int ks = 0; ks < 2; ks++) {
#pragma unroll
      for (int fm = 0; fm < 4; fm++)
        afL[ks][fm] = *(const short8*)(Lb + ((abase + fm * 4096) ^ (ks << 6)));
#pragma unroll
      for (int fn = 0; fn < 2; fn++)
        bfL[ks][fn] = *(const short8*)(Lb + ((bbase + fn * 8192) ^ (ks << 6)));
    }
    if (kt + 1 < nt) stageB(buf ^ 1, 1, (kt + 1) * 64);
    __builtin_amdgcn_s_barrier();
    asm volatile("s_waitcnt lgkmcnt(0)" ::: "memory");
    __builtin_amdgcn_sched_barrier(0);
    __builtin_amdgcn_s_setprio(1);
#pragma unroll
    for (int ks = 0; ks < 2; ks++)
#pragma unroll
      for (int fm = 0; fm < 4; fm++)
#pragma unroll
        for (int fn = 0; fn < 2; fn++)
          acc[fm][fn] = __builtin_amdgcn_mfma_f32_16x16x32_bf16(afL[ks][fm], bfL[ks][fn], acc[fm][fn], 0, 0, 0);
    __builtin_amdgcn_s_setprio(0);
    __builtin_amdgcn_s_barrier();

    // ---------- P2: Q2 (fmL x fnH) ----------
#pragma unroll
    for (int ks = 0; ks < 2; ks++)
#pragma unroll
      for (int fn = 0; fn < 2; fn++)
        bfH[ks][fn] = *(const short8*)(Lb + ((bbase + (2 + fn) * 8192) ^ (ks << 6)));
    if (kt + 2 < nt) stageA(buf, 0, ko2);
    __builtin_amdgcn_s_barrier();
    asm volatile("s_waitcnt lgkmcnt(0)" ::: "memory");
    __builtin_amdgcn_sched_barrier(0);
    __builtin_amdgcn_s_setprio(1);
#pragma unroll
    for (int ks = 0; ks < 2; ks++)
#pragma unroll
      for (int fm = 0; fm < 4; fm++)
#pragma unroll
        for (int fn = 0; fn < 2; fn++)
          acc[fm][2 + fn] = __builtin_amdgcn_mfma_f32_16x16x32_bf16(afL[ks][fm], bfH[ks][fn], acc[fm][2 + fn], 0, 0, 0);
    __builtin_amdgcn_s_setprio(0);
    __builtin_amdgcn_s_barrier();

    // ---------- P3: Q3 (fmH x fnL) ----------
#pragma unroll
    for (int ks = 0; ks < 2; ks++)
#pragma unroll
      for (int fm = 0; fm < 4; fm++)
        afH[ks][fm] = *(const short8*)(Lb + ((abase + (4 + fm) * 4096) ^ (ks << 6)));
    if (kt + 2 < nt) stageB(buf, 0, ko2);
    __builtin_amdgcn_s_barrier();
    asm volatile("s_waitcnt lgkmcnt(0)" ::: "memory");
    __builtin_amdgcn_sched_barrier(0);
    __builtin_amdgcn_s_setprio(1);
#pragma unroll
    for (int ks = 0; ks < 2; ks++)
#pragma unroll
      for (int fm = 0; fm < 4; fm++)
#pragma unroll
        for (int fn = 0; fn < 2; fn++)
          acc[4 + fm][fn] = __builtin_amdgcn_mfma_f32_16x16x32_bf16(afH[ks][fm], bfL[ks][fn], acc[4 + fm][fn], 0, 0, 0);
    __builtin_amdgcn_s_setprio(0);
    __builtin_amdgcn_s_barrier();

    // ---------- P4: Q4 (fmH x fnH) ----------
    if (kt + 2 < nt) {
      stageA(buf, 1, ko2);
      asm volatile("s_waitcnt vmcnt(6)" ::: "memory");
    } else {
      asm volatile("s_waitcnt vmcnt(0)" ::: "memory");
    }
    __builtin_amdgcn_sched_barrier(0);
    __builtin_amdgcn_s_barrier();
    __builtin_amdgcn_s_setprio(1);
#pragma unroll
    for (int ks = 0; ks < 2; ks++)
#pragma unroll
      for (int fm = 0; fm < 4; fm++)
#pragma unroll
        for (int fn = 0; fn < 2; fn++)
          acc[4 + fm][2 + fn] = __builtin_amdgcn_mfma_f32_16x16x32_bf16(afH[ks][fm], bfH[ks][fn], acc[4 + fm][2 + fn], 0, 0, 0);
    __builtin_amdgcn_s_setprio(0);
    __builtin_amdgcn_s_barrier();
  }

  if (EPI == 0) {
    unsigned short* Hout = (unsigned short*)outp;
#pragma unroll
    for (int fm = 0; fm < 8; fm++) {
      const int row0 = m0 + fm * 32 + wm * 16 + l4 * 4;
#pragma unroll
      for (int p = 0; p < 2; p++) {
        const int hcol = (n0 >> 1) + p * 64 + wn * 16 + l15;
        f32x4 c1 = acc[fm][2 * p], c3 = acc[fm][2 * p + 1];
#pragma unroll
        for (int rr = 0; rr < 4; rr++) {
          int rw = row0 + rr;
          if (AMODE == 0 || rw < M) {
            float v1 = c1[rr], v3 = c3[rr];
            float hv = (v1 / (1.0f + __expf(-v1))) * v3;
            Hout[(long)rw * OutW + hcol] = bf16r(hv);
          }
        }
      }
    }
  } else {
    unsigned short* O = (unsigned short*)outp;
#pragma unroll
    for (int fm = 0; fm < 8; fm++) {
#pragma unroll
      for (int rr = 0; rr < 4; rr++) {
        const int rw = m0 + fm * 32 + wm * 16 + l4 * 4 + rr;
        if (AMODE != 0 && rw >= M) continue;
        const long orow = (EPI == 2) ? (long)list[rw] : (long)rw;
#pragma unroll
        for (int fn = 0; fn < 4; fn++)
          O[orow * OutW + n0 + fn * 64 + wn * 16 + l15] = bf16r(acc[fm][fn][rr]);
      }
    }
  }
}

// ---------------- final combine: y = sbuf + w0*rbuf[2t] + w1*rbuf[2t+1] ----------------
__global__ __launch_bounds__(256) void combine_kernel(
    const unsigned short* __restrict__ sbuf, const unsigned short* __restrict__ rbuf,
    const float* __restrict__ cw, float* __restrict__ y) {
  const int t = blockIdx.x * 2 + (threadIdx.x >> 7);
  const int c8 = (threadIdx.x & 127) * 8;
  const float w0 = cw[t * 2], w1 = cw[t * 2 + 1];
  short8 s = *(const short8*)(sbuf + (long)t * 1024 + c8);
  short8 a = *(const short8*)(rbuf + (long)(t * 2) * 1024 + c8);
  short8 b = *(const short8*)(rbuf + (long)(t * 2 + 1) * 1024 + c8);
  float* yp = y + (long)t * 1024 + c8;
  float ov[8];
#pragma unroll
  for (int i = 0; i < 8; i++)
    ov[i] = bf2f((unsigned short)s[i]) + w0 * bf2f((unsigned short)a[i]) +
            w1 * bf2f((unsigned short)b[i]);
  *(float4*)(yp)     = make_float4(ov[0], ov[1], ov[2], ov[3]);
  *(float4*)(yp + 4) = make_float4(ov[4], ov[5], ov[6], ov[7]);
}

// ---------------- launch ----------------
extern "C" void kernel_launch(void* const* d_in, const int* in_sizes, int n_in,
                              void* d_out, int out_size, void* d_ws, size_t ws_size,
                              hipStream_t stream) {
  const float* x  = (const float*)d_in[0];
  const float* gw = (const float*)d_in[1];
  const float* W1 = (const float*)d_in[2];
  const float* W3 = (const float*)d_in[3];
  const float* W2 = (const float*)d_in[4];
  const float* Ws1 = (const float*)d_in[5];
  const float* Ws3 = (const float*)d_in[6];
  const float* Ws2 = (const float*)d_in[7];
  float* y = (float*)d_out;

  char* ws = (char*)d_ws;
  unsigned short* xb    = (unsigned short*)(ws + 0);            //  64 MB [T][1024]
  unsigned short* wt13  = (unsigned short*)(ws + 67108864L);    //  32 MB [4][4096][1024] (ilv64)
  unsigned short* wt2   = (unsigned short*)(ws + 100663296L);   //  16 MB [4][1024][2048]
  unsigned short* wts13 = (unsigned short*)(ws + 117440512L);   //   4 MB [2048][1024] (ilv64)
  unsigned short* wts2  = (unsigned short*)(ws + 121634816L);   //   2 MB [1024][1024]
  unsigned short* hbuf  = (unsigned short*)(ws + 123731968L);   // 128 MB [T][2048]
  unsigned short* rbuf  = (unsigned short*)(ws + 257949696L);   // 128 MB [2T][1024] bf16
  unsigned short* sbuf  = (unsigned short*)(ws + 392167424L);   //  64 MB [T][1024] bf16
  int*   list = (int*)(ws + 459276288L);                        // [4][T] tok*2+rank
  float* cw   = (float*)(ws + 459800576L);                      // [2T] token-indexed
  int*   cnt  = (int*)(ws + 460062720L);                        // [4]

  hipMemsetAsync(cnt, 0, 16, stream);

  transpose_bf16_kernel<1><<<dim3(64, 32, 4), dim3(32, 8), 0, stream>>>(
      W1, wt13, 1024, 2048, 1024L * 2048, 4096L * 1024);
  transpose_bf16_kernel<2><<<dim3(64, 32, 4), dim3(32, 8), 0, stream>>>(
      W3, wt13, 1024, 2048, 1024L * 2048, 4096L * 1024);
  transpose_bf16_kernel<0><<<dim3(32, 64, 4), dim3(32, 8), 0, stream>>>(
      W2, wt2, 2048, 1024, 2048L * 1024, 1024L * 2048);
  transpose_bf16_kernel<1><<<dim3(32, 32, 1), dim3(32, 8), 0, stream>>>(
      Ws1, wts13, 1024, 1024, 0, 0);
  transpose_bf16_kernel<2><<<dim3(32, 32, 1), dim3(32, 8), 0, stream>>>(
      Ws3, wts13, 1024, 1024, 0, 0);
  transpose_bf16_kernel<0><<<dim3(32, 32, 1), dim3(32, 8), 0, stream>>>(
      Ws2, wts2, 1024, 1024, 0, 0);

  gating_cast_kernel<<<T_TOK / 64, 256, 0, stream>>>(x, gw, xb, list, cw, cnt);

  // shared expert: h_s -> hbuf [T][1024]; sbuf = h_s @ Ws2 (bf16)
  gemm256_kernel<0, 0><<<dim3(8, 128), 512, 131072, stream>>>(
      xb, wts13, hbuf, nullptr, nullptr, 1024, 1024);
  gemm256_kernel<1, 0><<<dim3(4, 128), 512, 131072, stream>>>(
      hbuf, wts2, sbuf, nullptr, nullptr, 1024, 1024);

  // routed experts, sequential (hbuf reuse); ffn2 writes rbuf[tok*2+rank] (no RMW)
  for (int e = 0; e < NE; e++) {
    gemm256_kernel<0, 1><<<dim3(16, 128), 512, 131072, stream>>>(
        xb, wt13 + (long)e * 4096 * 1024, hbuf, list + e * T_TOK, cnt + e, 1024, 2048);
    gemm256_kernel<2, 2><<<dim3(4, 128), 512, 131072, stream>>>(
        hbuf, wt2 + (long)e * 1024 * 2048, rbuf, list + e * T_TOK, cnt + e, 2048, 1024);
  }

  combine_kernel<<<T_TOK / 2, 256, 0, stream>>>(sbuf, rbuf, cw, y);
}

// Round 7
// 1326.609 us; speedup vs baseline: 1.4266x; 1.4266x over previous
//
#include <hip/hip_runtime.h>
#include <hip/hip_bf16.h>
#include <cstdint>

#define T_TOK 32768
#define DIMD  1024
#define HID   2048
#define HSH   1024
#define NE    4

typedef __attribute__((ext_vector_type(8))) short short8;
typedef __attribute__((ext_vector_type(4))) float f32x4;

typedef const __attribute__((address_space(1))) void* gas_ptr;
typedef __attribute__((address_space(3))) void* las_ptr;

__device__ __forceinline__ void load_lds16(const void* g, void* l) {
  __builtin_amdgcn_global_load_lds((gas_ptr)g, (las_ptr)l, 16, 0, 0);
}

__device__ __forceinline__ unsigned short bf16r(float f) {
  union { float f; uint32_t u; } c; c.f = f;
  uint32_t u = c.u;
  uint32_t r = (u + 0x7FFFu + ((u >> 16) & 1u)) >> 16;
  return (unsigned short)r;
}

__device__ __forceinline__ float bf2f(unsigned short u) {
  union { uint32_t u; float f; } c; c.u = ((uint32_t)u) << 16; return c.f;
}

// ---------------- transpose fp32 [R][C] -> bf16 [C][R] ----------------
template <int TMODE>
__global__ __launch_bounds__(256) void transpose_bf16_kernel(
    const float* __restrict__ src, unsigned short* __restrict__ dst,
    int R, int C, long srcBS, long dstBS) {
  __shared__ float tile[32][33];
  const float* s = src + (long)blockIdx.z * srcBS;
  unsigned short* d = dst + (long)blockIdx.z * dstBS;
  int c0 = blockIdx.x * 32, r0 = blockIdx.y * 32;
  int tx = threadIdx.x, ty = threadIdx.y;
#pragma unroll
  for (int i = 0; i < 4; i++)
    tile[ty + i * 8][tx] = s[(long)(r0 + ty + i * 8) * C + c0 + tx];
  __syncthreads();
#pragma unroll
  for (int i = 0; i < 4; i++) {
    int c = c0 + ty + i * 8;
    int orow = (TMODE == 0) ? c : (((c >> 6) << 7) + (c & 63) + (TMODE == 2 ? 64 : 0));
    d[(long)orow * R + r0 + tx] = bf16r(tile[tx][ty + i * 8]);
  }
}

// ---------------- gating + x cast, block-aggregated list build ----------------
__global__ __launch_bounds__(256) void gating_cast_kernel(
    const float* __restrict__ x, const float* __restrict__ gw,
    unsigned short* __restrict__ xb,
    int* __restrict__ list, float* __restrict__ cw, int* __restrict__ cnt) {
  __shared__ int   se[128];
  __shared__ float sw[128];
  __shared__ int   sloc[128];
  __shared__ int   sbase[NE];
  const int lane = threadIdx.x & 63;
  const int wid = threadIdx.x >> 6;
  const int tb = blockIdx.x * 64;

  for (int j = 0; j < 16; j++) {
    const int tl = wid * 16 + j;
    const long t = tb + tl;
    const float4* xp = (const float4*)(x + t * DIMD);
    double acc[NE] = {0.0, 0.0, 0.0, 0.0};
    float4 xv[4];
#pragma unroll
    for (int i = 0; i < 4; i++) {
      xv[i] = xp[i * 64 + lane];
#pragma unroll
      for (int e = 0; e < NE; e++) {
        float4 gv = ((const float4*)(gw + e * DIMD))[i * 64 + lane];
        acc[e] += (double)xv[i].x * gv.x + (double)xv[i].y * gv.y +
                  (double)xv[i].z * gv.z + (double)xv[i].w * gv.w;
      }
    }
    ushort4* xbp = (ushort4*)(xb + t * DIMD);
#pragma unroll
    for (int i = 0; i < 4; i++) {
      ushort4 o;
      o.x = bf16r(xv[i].x); o.y = bf16r(xv[i].y);
      o.z = bf16r(xv[i].z); o.w = bf16r(xv[i].w);
      xbp[i * 64 + lane] = o;
    }
#pragma unroll
    for (int e = 0; e < NE; e++)
#pragma unroll
      for (int s = 32; s > 0; s >>= 1) acc[e] += __shfl_xor(acc[e], s, 64);
    if (lane == 0) {
      double m = acc[0];
      for (int e = 1; e < NE; e++) if (acc[e] > m) m = acc[e];
      double p[NE]; double s = 0.0;
      for (int e = 0; e < NE; e++) { p[e] = exp(acc[e] - m); s += p[e]; }
      int e0 = 0;
      for (int e = 1; e < NE; e++) if (p[e] > p[e0]) e0 = e;
      int e1 = (e0 == 0) ? 1 : 0;
      for (int e = 0; e < NE; e++) { if (e == e0) continue; if (p[e] > p[e1]) e1 = e; }
      se[tl * 2]     = e0; sw[tl * 2]     = (float)(p[e0] / s);
      se[tl * 2 + 1] = e1; sw[tl * 2 + 1] = (float)(p[e1] / s);
    }
  }
  __syncthreads();
  const int tid = threadIdx.x;
  if (tid < NE) {
    int c = 0;
    for (int s = 0; s < 128; s++)
      if (se[s] == tid) sloc[s] = c++;
    sbase[tid] = atomicAdd(&cnt[tid], c);
  }
  __syncthreads();
  if (tid < 128) {
    int e = se[tid];
    int pos = sbase[e] + sloc[tid];
    list[e * T_TOK + pos] = ((tb + (tid >> 1)) << 1) | (tid & 1);
    cw[tb * 2 + tid] = sw[tid];
  }
}

// ---------------- 256x256x64 8-wave GEMM, 8-phase schedule ----------------
// Block map (r7): supertiles (4n x 8m = 32 wgs) round-robin across XCDs:
//   xcd = orig&7, loc = orig>>3, s = (loc>>5)*8 + xcd, r = loc&31.
// Per XCD: sx = s%scols is FIXED (B-panel set pinned to the XCD's L2) and
// sy coverage is STRIDED -> M-pruning (m0>=M early exit) removes the same
// fraction of supertiles from every XCD (r6's map concentrated sy per XCD
// and idled XCDs 4-7 on routed dispatches). Bijective iff nwg%256==0.
template <int EPI, int AMODE>
__global__ __launch_bounds__(512, 2) void gemm256_kernel(
    const unsigned short* __restrict__ A, const unsigned short* __restrict__ Bt,
    void* __restrict__ outp, const int* __restrict__ list,
    const int* __restrict__ cntp, int K, int OutW) {
  extern __shared__ char ldsb[];  // 131072 bytes
  const int tid = threadIdx.x, lane = tid & 63;
  const int wid = tid >> 6;
  const int wm = wid >> 2, wn = wid & 3;
  const int l15 = lane & 15, l4 = lane >> 4;

  const int gx = gridDim.x;
  const int orig = blockIdx.y * gx + blockIdx.x;
  const int xcd = orig & 7, loc = orig >> 3;
  const int s = (loc >> 5) * 8 + xcd, r = loc & 31;
  const int scols = gx >> 2;
  const int sx = s % scols, sy = s / scols;
  const int n0 = (sx * 4 + (r & 3)) * 256;
  const int m0 = (sy * 8 + (r >> 2)) * 256;

  int M = 0x7fffffff;
  if (AMODE != 0) {
    M = *cntp;
    if (m0 >= M) return;
  }

  const unsigned short* pA[4];
  const unsigned short* pB[4];
  {
    const int rb = tid >> 3;
    const int cs = (tid & 7) ^ (rb & 7);
#pragma unroll
    for (int j = 0; j < 4; j++) {
      int rr = j * 64 + rb;
      int arow = m0 + rr;
      long ga;
      if (AMODE == 1)      ga = list[arow < M ? arow : M - 1] >> 1;
      else if (AMODE == 2) ga = (arow < M ? arow : M - 1);
      else                 ga = arow;
      pA[j] = A + ga * (long)K + cs * 8;
      pB[j] = Bt + (long)(n0 + rr) * K + cs * 8;
    }
  }

  auto stageA = [&](int buf, int half, int koff) {
    char* d = ldsb + buf * 65536 + half * 16384 + tid * 16;
    load_lds16(pA[half * 2 + 0] + koff, d);
    load_lds16(pA[half * 2 + 1] + koff, d + 8192);
  };
  auto stageB = [&](int buf, int half, int koff) {
    char* d = ldsb + buf * 65536 + 32768 + half * 16384 + tid * 16;
    load_lds16(pB[half * 2 + 0] + koff, d);
    load_lds16(pB[half * 2 + 1] + koff, d + 8192);
  };

  const int sw8 = l15 & 7;
  const int abase = (wm * 16 + l15) * 128 + ((l4 ^ sw8) * 16);
  const int bbase = 32768 + (wn * 16 + l15) * 128 + ((l4 ^ sw8) * 16);

  f32x4 acc[8][4] = {};
  const int nt = K >> 6;

  stageA(0, 0, 0); stageA(0, 1, 0); stageB(0, 0, 0); stageB(0, 1, 0);
  if (nt > 1) { stageA(1, 0, 64); stageB(1, 0, 64); stageA(1, 1, 64); }
  if (nt > 1) asm volatile("s_waitcnt vmcnt(6)" ::: "memory");
  else        asm volatile("s_waitcnt vmcnt(0)" ::: "memory");
  __builtin_amdgcn_sched_barrier(0);
  __builtin_amdgcn_s_barrier();

  for (int kt = 0; kt < nt; ++kt) {
    const int buf = kt & 1;
    const char* Lb = ldsb + buf * 65536;
    const int ko2 = (kt + 2) * 64;
    short8 afL[2][4], afH[2][4], bfL[2][2], bfH[2][2];

    // ---------- P1: Q1 (fmL x fnL) ----------
#pragma unroll
    for (int ks = 0; ks < 2; ks++) {
#pragma unroll
      for (int fm = 0; fm < 4; fm++)
        afL[ks][fm] = *(const short8*)(Lb + ((abase + fm * 4096) ^ (ks << 6)));
#pragma unroll
      for (int fn = 0; fn < 2; fn++)
        bfL[ks][fn] = *(const short8*)(Lb + ((bbase + fn * 8192) ^ (ks << 6)));
    }
    if (kt + 1 < nt) stageB(buf ^ 1, 1, (kt + 1) * 64);
    __builtin_amdgcn_s_barrier();
    asm volatile("s_waitcnt lgkmcnt(0)" ::: "memory");
    __builtin_amdgcn_sched_barrier(0);
    __builtin_amdgcn_s_setprio(1);
#pragma unroll
    for (int ks = 0; ks < 2; ks++)
#pragma unroll
      for (int fm = 0; fm < 4; fm++)
#pragma unroll
        for (int fn = 0; fn < 2; fn++)
          acc[fm][fn] = __builtin_amdgcn_mfma_f32_16x16x32_bf16(afL[ks][fm], bfL[ks][fn], acc[fm][fn], 0, 0, 0);
    __builtin_amdgcn_s_setprio(0);
    __builtin_amdgcn_s_barrier();

    // ---------- P2: Q2 (fmL x fnH) ----------
#pragma unroll
    for (int ks = 0; ks < 2; ks++)
#pragma unroll
      for (int fn = 0; fn < 2; fn++)
        bfH[ks][fn] = *(const short8*)(Lb + ((bbase + (2 + fn) * 8192) ^ (ks << 6)));
    if (kt + 2 < nt) stageA(buf, 0, ko2);
    __builtin_amdgcn_s_barrier();
    asm volatile("s_waitcnt lgkmcnt(0)" ::: "memory");
    __builtin_amdgcn_sched_barrier(0);
    __builtin_amdgcn_s_setprio(1);
#pragma unroll
    for (int ks = 0; ks < 2; ks++)
#pragma unroll
      for (int fm = 0; fm < 4; fm++)
#pragma unroll
        for (int fn = 0; fn < 2; fn++)
          acc[fm][2 + fn] = __builtin_amdgcn_mfma_f32_16x16x32_bf16(afL[ks][fm], bfH[ks][fn], acc[fm][2 + fn], 0, 0, 0);
    __builtin_amdgcn_s_setprio(0);
    __builtin_amdgcn_s_barrier();

    // ---------- P3: Q3 (fmH x fnL) ----------
#pragma unroll
    for (int ks = 0; ks < 2; ks++)
#pragma unroll
      for (int fm = 0; fm < 4; fm++)
        afH[ks][fm] = *(const short8*)(Lb + ((abase + (4 + fm) * 4096) ^ (ks << 6)));
    if (kt + 2 < nt) stageB(buf, 0, ko2);
    __builtin_amdgcn_s_barrier();
    asm volatile("s_waitcnt lgkmcnt(0)" ::: "memory");
    __builtin_amdgcn_sched_barrier(0);
    __builtin_amdgcn_s_setprio(1);
#pragma unroll
    for (int ks = 0; ks < 2; ks++)
#pragma unroll
      for (int fm = 0; fm < 4; fm++)
#pragma unroll
        for (int fn = 0; fn < 2; fn++)
          acc[4 + fm][fn] = __builtin_amdgcn_mfma_f32_16x16x32_bf16(afH[ks][fm], bfL[ks][fn], acc[4 + fm][fn], 0, 0, 0);
    __builtin_amdgcn_s_setprio(0);
    __builtin_amdgcn_s_barrier();

    // ---------- P4: Q4 (fmH x fnH) ----------
    if (kt + 2 < nt) {
      stageA(buf, 1, ko2);
      asm volatile("s_waitcnt vmcnt(6)" ::: "memory");
    } else {
      asm volatile("s_waitcnt vmcnt(0)" ::: "memory");
    }
    __builtin_amdgcn_sched_barrier(0);
    __builtin_amdgcn_s_barrier();
    __builtin_amdgcn_s_setprio(1);
#pragma unroll
    for (int ks = 0; ks < 2; ks++)
#pragma unroll
      for (int fm = 0; fm < 4; fm++)
#pragma unroll
        for (int fn = 0; fn < 2; fn++)
          acc[4 + fm][2 + fn] = __builtin_amdgcn_mfma_f32_16x16x32_bf16(afH[ks][fm], bfH[ks][fn], acc[4 + fm][2 + fn], 0, 0, 0);
    __builtin_amdgcn_s_setprio(0);
    __builtin_amdgcn_s_barrier();
  }

  if (EPI == 0) {
    unsigned short* Hout = (unsigned short*)outp;
#pragma unroll
    for (int fm = 0; fm < 8; fm++) {
      const int row0 = m0 + fm * 32 + wm * 16 + l4 * 4;
#pragma unroll
      for (int p = 0; p < 2; p++) {
        const int hcol = (n0 >> 1) + p * 64 + wn * 16 + l15;
        f32x4 c1 = acc[fm][2 * p], c3 = acc[fm][2 * p + 1];
#pragma unroll
        for (int rr = 0; rr < 4; rr++) {
          int rw = row0 + rr;
          if (AMODE == 0 || rw < M) {
            float v1 = c1[rr], v3 = c3[rr];
            float hv = (v1 / (1.0f + __expf(-v1))) * v3;
            Hout[(long)rw * OutW + hcol] = bf16r(hv);
          }
        }
      }
    }
  } else {
    unsigned short* O = (unsigned short*)outp;
#pragma unroll
    for (int fm = 0; fm < 8; fm++) {
#pragma unroll
      for (int rr = 0; rr < 4; rr++) {
        const int rw = m0 + fm * 32 + wm * 16 + l4 * 4 + rr;
        if (AMODE != 0 && rw >= M) continue;
        const long orow = (EPI == 2) ? (long)list[rw] : (long)rw;
#pragma unroll
        for (int fn = 0; fn < 4; fn++)
          O[orow * OutW + n0 + fn * 64 + wn * 16 + l15] = bf16r(acc[fm][fn][rr]);
      }
    }
  }
}

// ---------------- final combine: y = sbuf + w0*rbuf[2t] + w1*rbuf[2t+1] ----------------
__global__ __launch_bounds__(256) void combine_kernel(
    const unsigned short* __restrict__ sbuf, const unsigned short* __restrict__ rbuf,
    const float* __restrict__ cw, float* __restrict__ y) {
  const int t = blockIdx.x * 2 + (threadIdx.x >> 7);
  const int c8 = (threadIdx.x & 127) * 8;
  const float w0 = cw[t * 2], w1 = cw[t * 2 + 1];
  short8 s = *(const short8*)(sbuf + (long)t * 1024 + c8);
  short8 a = *(const short8*)(rbuf + (long)(t * 2) * 1024 + c8);
  short8 b = *(const short8*)(rbuf + (long)(t * 2 + 1) * 1024 + c8);
  float* yp = y + (long)t * 1024 + c8;
  float ov[8];
#pragma unroll
  for (int i = 0; i < 8; i++)
    ov[i] = bf2f((unsigned short)s[i]) + w0 * bf2f((unsigned short)a[i]) +
            w1 * bf2f((unsigned short)b[i]);
  *(float4*)(yp)     = make_float4(ov[0], ov[1], ov[2], ov[3]);
  *(float4*)(yp + 4) = make_float4(ov[4], ov[5], ov[6], ov[7]);
}

// ---------------- launch ----------------
extern "C" void kernel_launch(void* const* d_in, const int* in_sizes, int n_in,
                              void* d_out, int out_size, void* d_ws, size_t ws_size,
                              hipStream_t stream) {
  const float* x  = (const float*)d_in[0];
  const float* gw = (const float*)d_in[1];
  const float* W1 = (const float*)d_in[2];
  const float* W3 = (const float*)d_in[3];
  const float* W2 = (const float*)d_in[4];
  const float* Ws1 = (const float*)d_in[5];
  const float* Ws3 = (const float*)d_in[6];
  const float* Ws2 = (const float*)d_in[7];
  float* y = (float*)d_out;

  char* ws = (char*)d_ws;
  unsigned short* xb    = (unsigned short*)(ws + 0);            //  64 MB [T][1024]
  unsigned short* wt13  = (unsigned short*)(ws + 67108864L);    //  32 MB [4][4096][1024] (ilv64)
  unsigned short* wt2   = (unsigned short*)(ws + 100663296L);   //  16 MB [4][1024][2048]
  unsigned short* wts13 = (unsigned short*)(ws + 117440512L);   //   4 MB [2048][1024] (ilv64)
  unsigned short* wts2  = (unsigned short*)(ws + 121634816L);   //   2 MB [1024][1024]
  unsigned short* hbuf  = (unsigned short*)(ws + 123731968L);   // 128 MB [T][2048]
  unsigned short* rbuf  = (unsigned short*)(ws + 257949696L);   // 128 MB [2T][1024] bf16
  unsigned short* sbuf  = (unsigned short*)(ws + 392167424L);   //  64 MB [T][1024] bf16
  int*   list = (int*)(ws + 459276288L);                        // [4][T] tok*2+rank
  float* cw   = (float*)(ws + 459800576L);                      // [2T] token-indexed
  int*   cnt  = (int*)(ws + 460062720L);                        // [4]

  hipMemsetAsync(cnt, 0, 16, stream);

  transpose_bf16_kernel<1><<<dim3(64, 32, 4), dim3(32, 8), 0, stream>>>(
      W1, wt13, 1024, 2048, 1024L * 2048, 4096L * 1024);
  transpose_bf16_kernel<2><<<dim3(64, 32, 4), dim3(32, 8), 0, stream>>>(
      W3, wt13, 1024, 2048, 1024L * 2048, 4096L * 1024);
  transpose_bf16_kernel<0><<<dim3(32, 64, 4), dim3(32, 8), 0, stream>>>(
      W2, wt2, 2048, 1024, 2048L * 1024, 1024L * 2048);
  transpose_bf16_kernel<1><<<dim3(32, 32, 1), dim3(32, 8), 0, stream>>>(
      Ws1, wts13, 1024, 1024, 0, 0);
  transpose_bf16_kernel<2><<<dim3(32, 32, 1), dim3(32, 8), 0, stream>>>(
      Ws3, wts13, 1024, 1024, 0, 0);
  transpose_bf16_kernel<0><<<dim3(32, 32, 1), dim3(32, 8), 0, stream>>>(
      Ws2, wts2, 1024, 1024, 0, 0);

  gating_cast_kernel<<<T_TOK / 64, 256, 0, stream>>>(x, gw, xb, list, cw, cnt);

  // shared expert: h_s -> hbuf [T][1024]; sbuf = h_s @ Ws2 (bf16)
  gemm256_kernel<0, 0><<<dim3(8, 128), 512, 131072, stream>>>(
      xb, wts13, hbuf, nullptr, nullptr, 1024, 1024);
  gemm256_kernel<1, 0><<<dim3(4, 128), 512, 131072, stream>>>(
      hbuf, wts2, sbuf, nullptr, nullptr, 1024, 1024);

  // routed experts, sequential (hbuf reuse); ffn2 writes rbuf[tok*2+rank] (no RMW)
  for (int e = 0; e < NE; e++) {
    gemm256_kernel<0, 1><<<dim3(16, 128), 512, 131072, stream>>>(
        xb, wt13 + (long)e * 4096 * 1024, hbuf, list + e * T_TOK, cnt + e, 1024, 2048);
    gemm256_kernel<2, 2><<<dim3(4, 128), 512, 131072, stream>>>(
        hbuf, wt2 + (long)e * 1024 * 2048, rbuf, list + e * T_TOK, cnt + e, 2048, 1024);
  }

  combine_kernel<<<T_TOK / 2, 256, 0, stream>>>(sbuf, rbuf, cw, y);
}